// Round 28
// baseline (2714.446 us; speedup 1.0000x reference)
//
#include <hip/hip_runtime.h>
#include <stdint.h>

#define TLEN   4096
#define DMODEL 2048
#define NPROJ  1024
#define NHEADS 16
#define IDXD   64
#define TOPK   128
#define KC     512   // BLIS/AOCL zen f32 kc (verified R21: panels {512x4})

// monotonic f32 -> orderable u32 (no NaN/Inf in this data)
__device__ __forceinline__ unsigned int f32_ord(float f) {
  unsigned int u = __float_as_uint(f);
  return (u & 0x80000000u) ? ~u : (u | 0x80000000u);
}

// Tiled projection GEMM body, bit-exact to verified R21 arithmetic:
// 4 K-panels of 512, each a zero-init sequential FMA chain, panels combined
// left-to-right with plain f32 adds.
// TRANS==0: out[h][t][d]   TRANS==1: out[h][d][t]
template<int TRANS>
__device__ __forceinline__
void proj_body(const float* __restrict__ X, const float* __restrict__ W,
               float* __restrict__ out, float* smem) {
  float (*As)[64] = (float(*)[64])smem;          // [k][m]
  float (*Bs)[64] = (float(*)[64])(smem + 2048); // [k][n]
  float (*cs)[65] = (float(*)[65])smem;          // transpose staging

  const int tid = threadIdx.x;
  const int bx = blockIdx.x;   // head (64 output cols)
  const int by = blockIdx.y;   // t-tile

  const int tx = tid & 15;
  const int ty = tid >> 4;

  float acc[4][4] = {};
  float ctot[4][4];

  const int lt = tid & 7;
  const int tt = tid >> 3;
  const int bc = tid >> 4;
  const int bn = (tid & 15) * 4;

  for (int ks = 0; ks < DMODEL; ks += 32) {
    const int h2 = ks >> 7;
    const int offs = ks & 127;
    {
      const float* ap = X + ((size_t)h2 * TLEN + (size_t)by * 64) * 128 + offs + lt * 4;
      #pragma unroll
      for (int i = 0; i < 2; i++) {
        int t = tt + i * 32;
        float4 v = *(const float4*)(ap + (size_t)t * 128);
        As[lt * 4 + 0][t] = v.x;
        As[lt * 4 + 1][t] = v.y;
        As[lt * 4 + 2][t] = v.z;
        As[lt * 4 + 3][t] = v.w;
      }
    }
    {
      #pragma unroll
      for (int i = 0; i < 2; i++) {
        int c = ks + bc + i * 16;
        float4 v = *(const float4*)(W + (size_t)c * NPROJ + bx * 64 + bn);
        *(float4*)&Bs[bc + i * 16][bn] = v;
      }
    }
    __syncthreads();
    #pragma unroll
    for (int kk = 0; kk < 32; kk++) {
      float4 a = *(const float4*)&As[kk][ty * 4];
      float4 b = *(const float4*)&Bs[kk][tx * 4];
      const float av[4] = {a.x, a.y, a.z, a.w};
      const float bv[4] = {b.x, b.y, b.z, b.w};
      #pragma unroll
      for (int i = 0; i < 4; i++)
        #pragma unroll
        for (int j = 0; j < 4; j++)
          acc[i][j] = fmaf(av[i], bv[j], acc[i][j]);
    }
    __syncthreads();
    if (((ks + 32) & (KC - 1)) == 0) {           // panel boundary
      const bool first = (ks + 32 == KC);
      #pragma unroll
      for (int i = 0; i < 4; i++)
        #pragma unroll
        for (int j = 0; j < 4; j++) {
          ctot[i][j] = first ? acc[i][j] : __fadd_rn(ctot[i][j], acc[i][j]);
          acc[i][j] = 0.0f;
        }
    }
  }

  if (TRANS == 0) {
    #pragma unroll
    for (int i = 0; i < 4; i++) {
      int m = by * 64 + ty * 4 + i;
      float4 v = make_float4(ctot[i][0], ctot[i][1], ctot[i][2], ctot[i][3]);
      *(float4*)(out + ((size_t)bx * TLEN + m) * IDXD + tx * 4) = v;
    }
  } else {
    #pragma unroll
    for (int i = 0; i < 4; i++)
      #pragma unroll
      for (int j = 0; j < 4; j++)
        cs[ty * 4 + i][tx * 4 + j] = ctot[i][j];
    __syncthreads();
    const int mm = tid & 63;
    const int dg = tid >> 6;
    #pragma unroll
    for (int p = 0; p < 16; p++) {
      int d = dg + p * 4;
      out[((size_t)bx * IDXD + d) * TLEN + (size_t)by * 64 + mm] = cs[mm][d];
    }
  }
}

// Fused: z=0 does Q-projection (row-major), z=1 does K-projection (transposed)
__global__ __launch_bounds__(256)
void proj_both(const float* __restrict__ q, const float* __restrict__ k,
               const float* __restrict__ Wq, const float* __restrict__ Wk,
               float* __restrict__ qidx, float* __restrict__ kT) {
  __shared__ float smem[64 * 65];
  if (blockIdx.z == 0) proj_body<0>(q, Wq, qidx, smem);
  else                 proj_body<1>(k, Wk, kT, smem);
}

// Fused score + exact top-128 (R22-R27-verified selection semantics).
// R28 changes: (a) LDS union (hist overlaps cand/ebuf) 23->14.6 KB to admit
// a 2nd resident block; (b) pass-1 histogram uses wave-aggregated atomics
// (leader-ballot, one atomic per distinct bucket). Counting semantics and
// all arithmetic unchanged -> bit-exact.
__global__ __launch_bounds__(1024)
void score_topk(const float* __restrict__ qidx,  // [H][T][64]
                const float* __restrict__ kT,    // [H][64][T]
                int* __restrict__ out) {         // [H][T][128]
  __shared__ float qs_t[IDXD][8];                // [d][q]
  union SelU {
    unsigned int hist[8][257];                   // phase 2 only
    struct {
      unsigned long long cand[8][TOPK];          // phases 3-4 only
      unsigned int ebuf[8][128];
    } g;
  };
  __shared__ SelU u;
  __shared__ unsigned int pivot[8];
  __shared__ int rrem[8];
  __shared__ int gcnt[8];
  __shared__ int ecnt[8];

  const int tid = threadIdx.x;
  const int lane = tid & 63;
  const int wv = tid >> 6;                       // 0..15

  // XCD swizzle: 2 heads per XCD -> kT head slices L2-resident
  const int flat = blockIdx.y * gridDim.x + blockIdx.x;   // 0..8191
  const int nf   = (flat & 7) * 1024 + (flat >> 3);
  const int h    = nf >> 9;
  const int t0   = (nf & 511) * 8;

  if (tid < 8) { pivot[tid] = 0; rrem[tid] = TOPK; gcnt[tid] = 0; ecnt[tid] = 0; }
  if (tid < 512)
    qs_t[tid & 63][tid >> 6] =
        qidx[((size_t)h * TLEN + t0 + (tid >> 6)) * IDXD + (tid & 63)];
  __syncthreads();

  // ---- phase 1: scores, strict d-ascending chain. k index = 4*tid + s ----
  float sc[8][4] = {};
  const float* kbp = kT + (size_t)h * IDXD * TLEN + 4 * tid;
  for (int d = 0; d < IDXD; d++) {
    const float4 va = *(const float4*)(kbp + (size_t)d * TLEN);
    const float kv[4] = {va.x, va.y, va.z, va.w};
    float qv[8];
    *(float4*)&qv[0] = *(const float4*)&qs_t[d][0];
    *(float4*)&qv[4] = *(const float4*)&qs_t[d][4];
    #pragma unroll
    for (int q = 0; q < 8; q++)
      #pragma unroll
      for (int s = 0; s < 4; s++) sc[q][s] = fmaf(qv[q], kv[s], sc[q][s]);
  }

  unsigned int ku[8][4];
  #pragma unroll
  for (int q = 0; q < 8; q++)
    #pragma unroll
    for (int s = 0; s < 4; s++) ku[q][s] = f32_ord(sc[q][s]);

  // ---- phase 2: 4-pass radix select, wave-parallel bucket scan ----
  for (int pass = 0; pass < 4; pass++) {
    const int shift = 24 - 8 * pass;
    const unsigned int pmask = (pass == 0) ? 0u : (0xFFFFFFFFu << (shift + 8));
    for (int i = tid; i < 8 * 257; i += 1024) ((unsigned int*)u.hist)[i] = 0;
    __syncthreads();
    if (pass == 0) {
      // wave-aggregated histogram: one atomic per distinct bucket per wave
      #pragma unroll
      for (int q = 0; q < 8; q++) {
        #pragma unroll
        for (int s = 0; s < 4; s++) {
          unsigned int b = ku[q][s] >> 24;
          bool pending = true;
          while (__any(pending ? 1 : 0)) {
            unsigned long long m = __ballot(pending ? 1 : 0);
            int leader = (int)(__ffsll((long long)m) - 1);
            unsigned int bl = __shfl(b, leader);
            bool same = pending && (b == bl);
            unsigned long long sm = __ballot(same ? 1 : 0);
            if (lane == leader)
              atomicAdd(&u.hist[q][bl], (unsigned int)__popcll(sm));
            if (same) pending = false;
          }
        }
      }
    } else {
      #pragma unroll
      for (int q = 0; q < 8; q++) {
        unsigned int pv = pivot[q];
        #pragma unroll
        for (int s = 0; s < 4; s++) {
          unsigned int k = ku[q][s];
          if ((k & pmask) == pv)
            atomicAdd(&u.hist[q][(k >> shift) & 255], 1u);
        }
      }
    }
    __syncthreads();
    if (wv < 8) {
      // wave wv scans row wv: lane l holds buckets 255-4l..252-4l (desc order)
      const int rq = rrem[wv];
      unsigned int c0 = u.hist[wv][255 - 4 * lane];
      unsigned int c1 = u.hist[wv][254 - 4 * lane];
      unsigned int c2 = u.hist[wv][253 - 4 * lane];
      unsigned int c3 = u.hist[wv][252 - 4 * lane];
      unsigned int lsum = c0 + c1 + c2 + c3;
      unsigned int x = lsum;
      #pragma unroll
      for (int off = 1; off < 64; off <<= 1) {
        unsigned int y = __shfl_up(x, off);
        if (lane >= off) x += y;
      }
      const unsigned int excl = x - lsum;   // keys above this lane's buckets
      if ((int)excl < rq && (int)(excl + lsum) >= rq) {
        unsigned int cum = excl;
        unsigned int cc[4] = {c0, c1, c2, c3};
        #pragma unroll
        for (int i = 0; i < 4; i++) {
          if ((int)(cum + cc[i]) >= rq) {
            rrem[wv] = rq - (int)cum;
            pivot[wv] |= (unsigned int)(255 - 4 * lane - i) << shift;
            break;
          }
          cum += cc[i];
        }
      }
    }
    __syncthreads();
  }

  // sentinel-init candidates (hist no longer read; union now owns cand/ebuf)
  if (tid < 8 * TOPK)
    ((unsigned long long*)u.g.cand)[tid] = 0x00000000FFFFFFFFull;
  __syncthreads();

  // ---- phase 3: gather. > pivot all in; == pivot take smallest indices ----
  #pragma unroll
  for (int q = 0; q < 8; q++) {
    unsigned int pv = pivot[q];
    #pragma unroll
    for (int s = 0; s < 4; s++) {
      unsigned int k = ku[q][s];
      unsigned int idx = 4 * tid + s;
      if (k > pv) {
        int pos = atomicAdd(&gcnt[q], 1);
        if (pos < TOPK)
          u.g.cand[q][pos] = ((unsigned long long)k << 32) | (unsigned int)(~idx);
      } else if (k == pv) {
        int e = atomicAdd(&ecnt[q], 1);
        if (e < 128) u.g.ebuf[q][e] = idx;
      }
    }
  }
  __syncthreads();
  if (wv < 8) {
    // wave wv owns row wv: rank equal-indices, keep rrem smallest
    int e = ecnt[wv]; if (e > 128) e = 128;
    const int rq = rrem[wv];
    const int m = TOPK - rq;
    const unsigned long long pk = ((unsigned long long)pivot[wv]) << 32;
    for (int j = lane; j < e; j += 64) {
      unsigned int idx = u.g.ebuf[wv][j];
      int rank = 0;
      for (int i = 0; i < e; i++) rank += (u.g.ebuf[wv][i] < idx) ? 1 : 0;
      if (rank < rq) u.g.cand[wv][m + rank] = pk | (unsigned int)(~idx);
    }
    // wave-local writes; wave-local reads below — no block barrier needed

    // ---- phase 4: register bitonic sort, wave wv sorts row wv (desc) ----
    unsigned long long x0 = u.g.cand[wv][lane];        // element index lane
    unsigned long long x1 = u.g.cand[wv][lane + 64];   // element index lane+64
    #pragma unroll
    for (int k2 = 2; k2 <= 128; k2 <<= 1) {
      #pragma unroll
      for (int j = k2 >> 1; j > 0; j >>= 1) {
        if (j == 64) {
          unsigned long long hi = (x0 > x1) ? x0 : x1;
          unsigned long long lo = (x0 > x1) ? x1 : x0;
          x0 = hi; x1 = lo;
        } else {
          unsigned long long y0 = __shfl_xor(x0, j);
          unsigned long long y1 = __shfl_xor(x1, j);
          const bool ilow = ((lane & j) == 0);
          const bool dir0 = ((lane & k2) == 0);
          const bool dir1 = (((lane + 64) & k2) == 0);
          x0 = (dir0 == ilow) ? (x0 > y0 ? x0 : y0) : (x0 > y0 ? y0 : x0);
          x1 = (dir1 == ilow) ? (x1 > y1 ? x1 : y1) : (x1 > y1 ? y1 : x1);
        }
      }
    }
    int* orow = out + ((size_t)h * TLEN + t0 + wv) * TOPK;
    orow[lane]      = (int)(~(unsigned int)x0);
    orow[lane + 64] = (int)(~(unsigned int)x1);
  }
}

extern "C" void kernel_launch(void* const* d_in, const int* in_sizes, int n_in,
                              void* d_out, int out_size, void* d_ws, size_t ws_size,
                              hipStream_t stream) {
  const float* q  = (const float*)d_in[0];
  const float* k  = (const float*)d_in[1];
  const float* Wq = (const float*)d_in[2];
  const float* Wk = (const float*)d_in[3];

  const size_t idx_elems = (size_t)NHEADS * TLEN * IDXD;   // 4M elements
  if (ws_size < 2 * idx_elems * sizeof(float)) return;     // need 32MB scratch

  float* qidx = (float*)d_ws;                  // [H][T][64] f32, 16MB
  float* kT   = (float*)d_ws + idx_elems;      // [H][64][T] f32, 16MB

  dim3 gproj(NPROJ / 64, TLEN / 64, 2);
  proj_both<<<gproj, 256, 0, stream>>>(q, k, Wq, Wk, qidx, kT);

  dim3 gsc(TLEN / 8, NHEADS);
  score_topk<<<gsc, 1024, 0, stream>>>(qidx, kT, (int*)d_out);
}

// Round 29
// 1501.431 us; speedup vs baseline: 1.8079x; 1.8079x over previous
//
#include <hip/hip_runtime.h>
#include <stdint.h>

#define TLEN   4096
#define DMODEL 2048
#define NPROJ  1024
#define NHEADS 16
#define IDXD   64
#define TOPK   128
#define KC     512   // BLIS/AOCL zen f32 kc (verified R21: panels {512x4})

// monotonic f32 -> orderable u32 (no NaN/Inf in this data)
__device__ __forceinline__ unsigned int f32_ord(float f) {
  unsigned int u = __float_as_uint(f);
  return (u & 0x80000000u) ? ~u : (u | 0x80000000u);
}

// Tiled projection GEMM body, bit-exact to verified R21 arithmetic:
// 4 K-panels of 512, each a zero-init sequential FMA chain, panels combined
// left-to-right with plain f32 adds.
// TRANS==0: out[h][t][d]   TRANS==1: out[h][d][t]
template<int TRANS>
__device__ __forceinline__
void proj_body(const float* __restrict__ X, const float* __restrict__ W,
               float* __restrict__ out, float* smem) {
  float (*As)[64] = (float(*)[64])smem;          // [k][m]
  float (*Bs)[64] = (float(*)[64])(smem + 2048); // [k][n]
  float (*cs)[65] = (float(*)[65])smem;          // transpose staging

  const int tid = threadIdx.x;
  const int bx = blockIdx.x;   // head (64 output cols)
  const int by = blockIdx.y;   // t-tile

  const int tx = tid & 15;
  const int ty = tid >> 4;

  float acc[4][4] = {};
  float ctot[4][4];

  const int lt = tid & 7;
  const int tt = tid >> 3;
  const int bc = tid >> 4;
  const int bn = (tid & 15) * 4;

  for (int ks = 0; ks < DMODEL; ks += 32) {
    const int h2 = ks >> 7;
    const int offs = ks & 127;
    {
      const float* ap = X + ((size_t)h2 * TLEN + (size_t)by * 64) * 128 + offs + lt * 4;
      #pragma unroll
      for (int i = 0; i < 2; i++) {
        int t = tt + i * 32;
        float4 v = *(const float4*)(ap + (size_t)t * 128);
        As[lt * 4 + 0][t] = v.x;
        As[lt * 4 + 1][t] = v.y;
        As[lt * 4 + 2][t] = v.z;
        As[lt * 4 + 3][t] = v.w;
      }
    }
    {
      #pragma unroll
      for (int i = 0; i < 2; i++) {
        int c = ks + bc + i * 16;
        float4 v = *(const float4*)(W + (size_t)c * NPROJ + bx * 64 + bn);
        *(float4*)&Bs[bc + i * 16][bn] = v;
      }
    }
    __syncthreads();
    #pragma unroll
    for (int kk = 0; kk < 32; kk++) {
      float4 a = *(const float4*)&As[kk][ty * 4];
      float4 b = *(const float4*)&Bs[kk][tx * 4];
      const float av[4] = {a.x, a.y, a.z, a.w};
      const float bv[4] = {b.x, b.y, b.z, b.w};
      #pragma unroll
      for (int i = 0; i < 4; i++)
        #pragma unroll
        for (int j = 0; j < 4; j++)
          acc[i][j] = fmaf(av[i], bv[j], acc[i][j]);
    }
    __syncthreads();
    if (((ks + 32) & (KC - 1)) == 0) {           // panel boundary
      const bool first = (ks + 32 == KC);
      #pragma unroll
      for (int i = 0; i < 4; i++)
        #pragma unroll
        for (int j = 0; j < 4; j++) {
          ctot[i][j] = first ? acc[i][j] : __fadd_rn(ctot[i][j], acc[i][j]);
          acc[i][j] = 0.0f;
        }
    }
  }

  if (TRANS == 0) {
    #pragma unroll
    for (int i = 0; i < 4; i++) {
      int m = by * 64 + ty * 4 + i;
      float4 v = make_float4(ctot[i][0], ctot[i][1], ctot[i][2], ctot[i][3]);
      *(float4*)(out + ((size_t)bx * TLEN + m) * IDXD + tx * 4) = v;
    }
  } else {
    #pragma unroll
    for (int i = 0; i < 4; i++)
      #pragma unroll
      for (int j = 0; j < 4; j++)
        cs[ty * 4 + i][tx * 4 + j] = ctot[i][j];
    __syncthreads();
    const int mm = tid & 63;
    const int dg = tid >> 6;
    #pragma unroll
    for (int p = 0; p < 16; p++) {
      int d = dg + p * 4;
      out[((size_t)bx * IDXD + d) * TLEN + (size_t)by * 64 + mm] = cs[mm][d];
    }
  }
}

// Fused: z=0 does Q-projection (row-major), z=1 does K-projection (transposed)
__global__ __launch_bounds__(256)
void proj_both(const float* __restrict__ q, const float* __restrict__ k,
               const float* __restrict__ Wq, const float* __restrict__ Wk,
               float* __restrict__ qidx, float* __restrict__ kT) {
  __shared__ float smem[64 * 65];
  if (blockIdx.z == 0) proj_body<0>(q, Wq, qidx, smem);
  else                 proj_body<1>(k, Wk, kT, smem);
}

// Fused score + exact top-128 (R22-R27-verified selection semantics).
// R29: revert R28's ballot aggregation (direct atomics, R27 semantics);
// keep LDS union (hist overlaps cand/ebuf); __launch_bounds__(1024, 8)
// -> 8 waves/EU = 2 resident 16-wave blocks/CU (R27's (1024,4) capped at 1).
__global__ __launch_bounds__(1024, 8)
void score_topk(const float* __restrict__ qidx,  // [H][T][64]
                const float* __restrict__ kT,    // [H][64][T]
                int* __restrict__ out) {         // [H][T][128]
  __shared__ float qs_t[IDXD][8];                // [d][q]
  union SelU {
    unsigned int hist[8][257];                   // phase 2 only
    struct {
      unsigned long long cand[8][TOPK];          // phases 3-4 only
      unsigned int ebuf[8][128];
    } g;
  };
  __shared__ SelU u;
  __shared__ unsigned int pivot[8];
  __shared__ int rrem[8];
  __shared__ int gcnt[8];
  __shared__ int ecnt[8];

  const int tid = threadIdx.x;
  const int lane = tid & 63;
  const int wv = tid >> 6;                       // 0..15

  // XCD swizzle: 2 heads per XCD -> kT head slices L2-resident
  const int flat = blockIdx.y * gridDim.x + blockIdx.x;   // 0..8191
  const int nf   = (flat & 7) * 1024 + (flat >> 3);
  const int h    = nf >> 9;
  const int t0   = (nf & 511) * 8;

  if (tid < 8) { pivot[tid] = 0; rrem[tid] = TOPK; gcnt[tid] = 0; ecnt[tid] = 0; }
  if (tid < 512)
    qs_t[tid & 63][tid >> 6] =
        qidx[((size_t)h * TLEN + t0 + (tid >> 6)) * IDXD + (tid & 63)];
  __syncthreads();

  // ---- phase 1: scores, strict d-ascending chain. k index = 4*tid + s ----
  float sc[8][4] = {};
  const float* kbp = kT + (size_t)h * IDXD * TLEN + 4 * tid;
  for (int d = 0; d < IDXD; d++) {
    const float4 va = *(const float4*)(kbp + (size_t)d * TLEN);
    const float kv[4] = {va.x, va.y, va.z, va.w};
    float qv[8];
    *(float4*)&qv[0] = *(const float4*)&qs_t[d][0];
    *(float4*)&qv[4] = *(const float4*)&qs_t[d][4];
    #pragma unroll
    for (int q = 0; q < 8; q++)
      #pragma unroll
      for (int s = 0; s < 4; s++) sc[q][s] = fmaf(qv[q], kv[s], sc[q][s]);
  }

  unsigned int ku[8][4];
  #pragma unroll
  for (int q = 0; q < 8; q++)
    #pragma unroll
    for (int s = 0; s < 4; s++) ku[q][s] = f32_ord(sc[q][s]);

  // ---- phase 2: 4-pass radix select, wave-parallel bucket scan ----
  for (int pass = 0; pass < 4; pass++) {
    const int shift = 24 - 8 * pass;
    const unsigned int pmask = (pass == 0) ? 0u : (0xFFFFFFFFu << (shift + 8));
    for (int i = tid; i < 8 * 257; i += 1024) ((unsigned int*)u.hist)[i] = 0;
    __syncthreads();
    #pragma unroll
    for (int q = 0; q < 8; q++) {
      unsigned int pv = pivot[q];
      #pragma unroll
      for (int s = 0; s < 4; s++) {
        unsigned int k = ku[q][s];
        if ((k & pmask) == pv)
          atomicAdd(&u.hist[q][(k >> shift) & 255], 1u);
      }
    }
    __syncthreads();
    if (wv < 8) {
      // wave wv scans row wv: lane l holds buckets 255-4l..252-4l (desc order)
      const int rq = rrem[wv];
      unsigned int c0 = u.hist[wv][255 - 4 * lane];
      unsigned int c1 = u.hist[wv][254 - 4 * lane];
      unsigned int c2 = u.hist[wv][253 - 4 * lane];
      unsigned int c3 = u.hist[wv][252 - 4 * lane];
      unsigned int lsum = c0 + c1 + c2 + c3;
      unsigned int x = lsum;
      #pragma unroll
      for (int off = 1; off < 64; off <<= 1) {
        unsigned int y = __shfl_up(x, off);
        if (lane >= off) x += y;
      }
      const unsigned int excl = x - lsum;   // keys above this lane's buckets
      if ((int)excl < rq && (int)(excl + lsum) >= rq) {
        unsigned int cum = excl;
        unsigned int cc[4] = {c0, c1, c2, c3};
        #pragma unroll
        for (int i = 0; i < 4; i++) {
          if ((int)(cum + cc[i]) >= rq) {
            rrem[wv] = rq - (int)cum;
            pivot[wv] |= (unsigned int)(255 - 4 * lane - i) << shift;
            break;
          }
          cum += cc[i];
        }
      }
    }
    __syncthreads();
  }

  // sentinel-init candidates (hist no longer read; union now owns cand/ebuf)
  if (tid < 8 * TOPK)
    ((unsigned long long*)u.g.cand)[tid] = 0x00000000FFFFFFFFull;
  __syncthreads();

  // ---- phase 3: gather. > pivot all in; == pivot take smallest indices ----
  #pragma unroll
  for (int q = 0; q < 8; q++) {
    unsigned int pv = pivot[q];
    #pragma unroll
    for (int s = 0; s < 4; s++) {
      unsigned int k = ku[q][s];
      unsigned int idx = 4 * tid + s;
      if (k > pv) {
        int pos = atomicAdd(&gcnt[q], 1);
        if (pos < TOPK)
          u.g.cand[q][pos] = ((unsigned long long)k << 32) | (unsigned int)(~idx);
      } else if (k == pv) {
        int e = atomicAdd(&ecnt[q], 1);
        if (e < 128) u.g.ebuf[q][e] = idx;
      }
    }
  }
  __syncthreads();
  if (wv < 8) {
    // wave wv owns row wv: rank equal-indices, keep rrem smallest
    int e = ecnt[wv]; if (e > 128) e = 128;
    const int rq = rrem[wv];
    const int m = TOPK - rq;
    const unsigned long long pk = ((unsigned long long)pivot[wv]) << 32;
    for (int j = lane; j < e; j += 64) {
      unsigned int idx = u.g.ebuf[wv][j];
      int rank = 0;
      for (int i = 0; i < e; i++) rank += (u.g.ebuf[wv][i] < idx) ? 1 : 0;
      if (rank < rq) u.g.cand[wv][m + rank] = pk | (unsigned int)(~idx);
    }
    // wave-local writes; wave-local reads below — no block barrier needed

    // ---- phase 4: register bitonic sort, wave wv sorts row wv (desc) ----
    unsigned long long x0 = u.g.cand[wv][lane];        // element index lane
    unsigned long long x1 = u.g.cand[wv][lane + 64];   // element index lane+64
    #pragma unroll
    for (int k2 = 2; k2 <= 128; k2 <<= 1) {
      #pragma unroll
      for (int j = k2 >> 1; j > 0; j >>= 1) {
        if (j == 64) {
          unsigned long long hi = (x0 > x1) ? x0 : x1;
          unsigned long long lo = (x0 > x1) ? x1 : x0;
          x0 = hi; x1 = lo;
        } else {
          unsigned long long y0 = __shfl_xor(x0, j);
          unsigned long long y1 = __shfl_xor(x1, j);
          const bool ilow = ((lane & j) == 0);
          const bool dir0 = ((lane & k2) == 0);
          const bool dir1 = (((lane + 64) & k2) == 0);
          x0 = (dir0 == ilow) ? (x0 > y0 ? x0 : y0) : (x0 > y0 ? y0 : x0);
          x1 = (dir1 == ilow) ? (x1 > y1 ? x1 : y1) : (x1 > y1 ? y1 : x1);
        }
      }
    }
    int* orow = out + ((size_t)h * TLEN + t0 + wv) * TOPK;
    orow[lane]      = (int)(~(unsigned int)x0);
    orow[lane + 64] = (int)(~(unsigned int)x1);
  }
}

extern "C" void kernel_launch(void* const* d_in, const int* in_sizes, int n_in,
                              void* d_out, int out_size, void* d_ws, size_t ws_size,
                              hipStream_t stream) {
  const float* q  = (const float*)d_in[0];
  const float* k  = (const float*)d_in[1];
  const float* Wq = (const float*)d_in[2];
  const float* Wk = (const float*)d_in[3];

  const size_t idx_elems = (size_t)NHEADS * TLEN * IDXD;   // 4M elements
  if (ws_size < 2 * idx_elems * sizeof(float)) return;     // need 32MB scratch

  float* qidx = (float*)d_ws;                  // [H][T][64] f32, 16MB
  float* kT   = (float*)d_ws + idx_elems;      // [H][64][T] f32, 16MB

  dim3 gproj(NPROJ / 64, TLEN / 64, 2);
  proj_both<<<gproj, 256, 0, stream>>>(q, k, Wq, Wk, qidx, kT);

  dim3 gsc(TLEN / 8, NHEADS);
  score_topk<<<gsc, 1024, 0, stream>>>(qidx, kT, (int*)d_out);
}

// Round 30
// 1455.546 us; speedup vs baseline: 1.8649x; 1.0315x over previous
//
#include <hip/hip_runtime.h>
#include <stdint.h>

#define TLEN   4096
#define DMODEL 2048
#define NPROJ  1024
#define NHEADS 16
#define IDXD   64
#define TOPK   128
#define KC     512   // BLIS/AOCL zen f32 kc (verified R21: panels {512x4})

// monotonic f32 -> orderable u32 (no NaN/Inf in this data)
__device__ __forceinline__ unsigned int f32_ord(float f) {
  unsigned int u = __float_as_uint(f);
  return (u & 0x80000000u) ? ~u : (u | 0x80000000u);
}

// Tiled projection GEMM body, bit-exact to verified R21 arithmetic:
// 4 K-panels of 512, each a zero-init sequential FMA chain, panels combined
// left-to-right with plain f32 adds.
// TRANS==0: out[h][t][d]   TRANS==1: out[h][d][t]
template<int TRANS>
__device__ __forceinline__
void proj_body(const float* __restrict__ X, const float* __restrict__ W,
               float* __restrict__ out, float* smem) {
  float (*As)[64] = (float(*)[64])smem;          // [k][m]
  float (*Bs)[64] = (float(*)[64])(smem + 2048); // [k][n]
  float (*cs)[65] = (float(*)[65])smem;          // transpose staging

  const int tid = threadIdx.x;
  const int bx = blockIdx.x;   // head (64 output cols)
  const int by = blockIdx.y;   // t-tile

  const int tx = tid & 15;
  const int ty = tid >> 4;

  float acc[4][4] = {};
  float ctot[4][4];

  const int lt = tid & 7;
  const int tt = tid >> 3;
  const int bc = tid >> 4;
  const int bn = (tid & 15) * 4;

  for (int ks = 0; ks < DMODEL; ks += 32) {
    const int h2 = ks >> 7;
    const int offs = ks & 127;
    {
      const float* ap = X + ((size_t)h2 * TLEN + (size_t)by * 64) * 128 + offs + lt * 4;
      #pragma unroll
      for (int i = 0; i < 2; i++) {
        int t = tt + i * 32;
        float4 v = *(const float4*)(ap + (size_t)t * 128);
        As[lt * 4 + 0][t] = v.x;
        As[lt * 4 + 1][t] = v.y;
        As[lt * 4 + 2][t] = v.z;
        As[lt * 4 + 3][t] = v.w;
      }
    }
    {
      #pragma unroll
      for (int i = 0; i < 2; i++) {
        int c = ks + bc + i * 16;
        float4 v = *(const float4*)(W + (size_t)c * NPROJ + bx * 64 + bn);
        *(float4*)&Bs[bc + i * 16][bn] = v;
      }
    }
    __syncthreads();
    #pragma unroll
    for (int kk = 0; kk < 32; kk++) {
      float4 a = *(const float4*)&As[kk][ty * 4];
      float4 b = *(const float4*)&Bs[kk][tx * 4];
      const float av[4] = {a.x, a.y, a.z, a.w};
      const float bv[4] = {b.x, b.y, b.z, b.w};
      #pragma unroll
      for (int i = 0; i < 4; i++)
        #pragma unroll
        for (int j = 0; j < 4; j++)
          acc[i][j] = fmaf(av[i], bv[j], acc[i][j]);
    }
    __syncthreads();
    if (((ks + 32) & (KC - 1)) == 0) {           // panel boundary
      const bool first = (ks + 32 == KC);
      #pragma unroll
      for (int i = 0; i < 4; i++)
        #pragma unroll
        for (int j = 0; j < 4; j++) {
          ctot[i][j] = first ? acc[i][j] : __fadd_rn(ctot[i][j], acc[i][j]);
          acc[i][j] = 0.0f;
        }
    }
  }

  if (TRANS == 0) {
    #pragma unroll
    for (int i = 0; i < 4; i++) {
      int m = by * 64 + ty * 4 + i;
      float4 v = make_float4(ctot[i][0], ctot[i][1], ctot[i][2], ctot[i][3]);
      *(float4*)(out + ((size_t)bx * TLEN + m) * IDXD + tx * 4) = v;
    }
  } else {
    #pragma unroll
    for (int i = 0; i < 4; i++)
      #pragma unroll
      for (int j = 0; j < 4; j++)
        cs[ty * 4 + i][tx * 4 + j] = ctot[i][j];
    __syncthreads();
    const int mm = tid & 63;
    const int dg = tid >> 6;
    #pragma unroll
    for (int p = 0; p < 16; p++) {
      int d = dg + p * 4;
      out[((size_t)bx * IDXD + d) * TLEN + (size_t)by * 64 + mm] = cs[mm][d];
    }
  }
}

// Fused: z=0 does Q-projection (row-major), z=1 does K-projection (transposed)
__global__ __launch_bounds__(256)
void proj_both(const float* __restrict__ q, const float* __restrict__ k,
               const float* __restrict__ Wq, const float* __restrict__ Wk,
               float* __restrict__ qidx, float* __restrict__ kT) {
  __shared__ float smem[64 * 65];
  if (blockIdx.z == 0) proj_body<0>(q, Wq, qidx, smem);
  else                 proj_body<1>(k, Wk, kT, smem);
}

// Fused score + exact top-128 (R22-R27-verified selection semantics).
// R30: fit true live state under the 64-VGPR cap of (1024,8) — ku[][] array
// removed, f32_ord recomputed at each use (pure function of sc). Eliminates
// R29's spill (WRITE_SIZE 489MB -> 32MB expected). Semantics unchanged.
__global__ __launch_bounds__(1024, 8)
void score_topk(const float* __restrict__ qidx,  // [H][T][64]
                const float* __restrict__ kT,    // [H][64][T]
                int* __restrict__ out) {         // [H][T][128]
  __shared__ float qs_t[IDXD][8];                // [d][q]
  union SelU {
    unsigned int hist[8][257];                   // phase 2 only
    struct {
      unsigned long long cand[8][TOPK];          // phases 3-4 only
      unsigned int ebuf[8][128];
    } g;
  };
  __shared__ SelU u;
  __shared__ unsigned int pivot[8];
  __shared__ int rrem[8];
  __shared__ int gcnt[8];
  __shared__ int ecnt[8];

  const int tid = threadIdx.x;
  const int lane = tid & 63;
  const int wv = tid >> 6;                       // 0..15

  // XCD swizzle: 2 heads per XCD -> kT head slices L2-resident
  const int flat = blockIdx.y * gridDim.x + blockIdx.x;   // 0..8191
  const int nf   = (flat & 7) * 1024 + (flat >> 3);
  const int h    = nf >> 9;
  const int t0   = (nf & 511) * 8;

  if (tid < 8) { pivot[tid] = 0; rrem[tid] = TOPK; gcnt[tid] = 0; ecnt[tid] = 0; }
  if (tid < 512)
    qs_t[tid & 63][tid >> 6] =
        qidx[((size_t)h * TLEN + t0 + (tid >> 6)) * IDXD + (tid & 63)];
  __syncthreads();

  // ---- phase 1: scores, strict d-ascending chain. k index = 4*tid + s ----
  float sc[8][4] = {};
  const float* kbp = kT + (size_t)h * IDXD * TLEN + 4 * tid;
  for (int d = 0; d < IDXD; d++) {
    const float4 va = *(const float4*)(kbp + (size_t)d * TLEN);
    const float kv[4] = {va.x, va.y, va.z, va.w};
    float qv[8];
    *(float4*)&qv[0] = *(const float4*)&qs_t[d][0];
    *(float4*)&qv[4] = *(const float4*)&qs_t[d][4];
    #pragma unroll
    for (int q = 0; q < 8; q++)
      #pragma unroll
      for (int s = 0; s < 4; s++) sc[q][s] = fmaf(qv[q], kv[s], sc[q][s]);
  }

  // ---- phase 2: 4-pass radix select, wave-parallel bucket scan ----
  // (f32_ord recomputed from sc at each use — no persistent ku array)
  for (int pass = 0; pass < 4; pass++) {
    const int shift = 24 - 8 * pass;
    const unsigned int pmask = (pass == 0) ? 0u : (0xFFFFFFFFu << (shift + 8));
    for (int i = tid; i < 8 * 257; i += 1024) ((unsigned int*)u.hist)[i] = 0;
    __syncthreads();
    #pragma unroll
    for (int q = 0; q < 8; q++) {
      unsigned int pv = pivot[q];
      #pragma unroll
      for (int s = 0; s < 4; s++) {
        unsigned int k = f32_ord(sc[q][s]);
        if ((k & pmask) == pv)
          atomicAdd(&u.hist[q][(k >> shift) & 255], 1u);
      }
    }
    __syncthreads();
    if (wv < 8) {
      // wave wv scans row wv: lane l holds buckets 255-4l..252-4l (desc order)
      const int rq = rrem[wv];
      unsigned int c0 = u.hist[wv][255 - 4 * lane];
      unsigned int c1 = u.hist[wv][254 - 4 * lane];
      unsigned int c2 = u.hist[wv][253 - 4 * lane];
      unsigned int c3 = u.hist[wv][252 - 4 * lane];
      unsigned int lsum = c0 + c1 + c2 + c3;
      unsigned int x = lsum;
      #pragma unroll
      for (int off = 1; off < 64; off <<= 1) {
        unsigned int y = __shfl_up(x, off);
        if (lane >= off) x += y;
      }
      const unsigned int excl = x - lsum;   // keys above this lane's buckets
      if ((int)excl < rq && (int)(excl + lsum) >= rq) {
        unsigned int cum = excl;
        unsigned int cc[4] = {c0, c1, c2, c3};
        #pragma unroll
        for (int i = 0; i < 4; i++) {
          if ((int)(cum + cc[i]) >= rq) {
            rrem[wv] = rq - (int)cum;
            pivot[wv] |= (unsigned int)(255 - 4 * lane - i) << shift;
            break;
          }
          cum += cc[i];
        }
      }
    }
    __syncthreads();
  }

  // sentinel-init candidates (hist no longer read; union now owns cand/ebuf)
  if (tid < 8 * TOPK)
    ((unsigned long long*)u.g.cand)[tid] = 0x00000000FFFFFFFFull;
  __syncthreads();

  // ---- phase 3: gather. > pivot all in; == pivot take smallest indices ----
  #pragma unroll
  for (int q = 0; q < 8; q++) {
    unsigned int pv = pivot[q];
    #pragma unroll
    for (int s = 0; s < 4; s++) {
      unsigned int k = f32_ord(sc[q][s]);
      unsigned int idx = 4 * tid + s;
      if (k > pv) {
        int pos = atomicAdd(&gcnt[q], 1);
        if (pos < TOPK)
          u.g.cand[q][pos] = ((unsigned long long)k << 32) | (unsigned int)(~idx);
      } else if (k == pv) {
        int e = atomicAdd(&ecnt[q], 1);
        if (e < 128) u.g.ebuf[q][e] = idx;
      }
    }
  }
  __syncthreads();
  if (wv < 8) {
    // wave wv owns row wv: rank equal-indices, keep rrem smallest
    int e = ecnt[wv]; if (e > 128) e = 128;
    const int rq = rrem[wv];
    const int m = TOPK - rq;
    const unsigned long long pk = ((unsigned long long)pivot[wv]) << 32;
    for (int j = lane; j < e; j += 64) {
      unsigned int idx = u.g.ebuf[wv][j];
      int rank = 0;
      for (int i = 0; i < e; i++) rank += (u.g.ebuf[wv][i] < idx) ? 1 : 0;
      if (rank < rq) u.g.cand[wv][m + rank] = pk | (unsigned int)(~idx);
    }
    // wave-local writes; wave-local reads below — no block barrier needed

    // ---- phase 4: register bitonic sort, wave wv sorts row wv (desc) ----
    unsigned long long x0 = u.g.cand[wv][lane];        // element index lane
    unsigned long long x1 = u.g.cand[wv][lane + 64];   // element index lane+64
    #pragma unroll
    for (int k2 = 2; k2 <= 128; k2 <<= 1) {
      #pragma unroll
      for (int j = k2 >> 1; j > 0; j >>= 1) {
        if (j == 64) {
          unsigned long long hi = (x0 > x1) ? x0 : x1;
          unsigned long long lo = (x0 > x1) ? x1 : x0;
          x0 = hi; x1 = lo;
        } else {
          unsigned long long y0 = __shfl_xor(x0, j);
          unsigned long long y1 = __shfl_xor(x1, j);
          const bool ilow = ((lane & j) == 0);
          const bool dir0 = ((lane & k2) == 0);
          const bool dir1 = (((lane + 64) & k2) == 0);
          x0 = (dir0 == ilow) ? (x0 > y0 ? x0 : y0) : (x0 > y0 ? y0 : x0);
          x1 = (dir1 == ilow) ? (x1 > y1 ? x1 : y1) : (x1 > y1 ? y1 : x1);
        }
      }
    }
    int* orow = out + ((size_t)h * TLEN + t0 + wv) * TOPK;
    orow[lane]      = (int)(~(unsigned int)x0);
    orow[lane + 64] = (int)(~(unsigned int)x1);
  }
}

extern "C" void kernel_launch(void* const* d_in, const int* in_sizes, int n_in,
                              void* d_out, int out_size, void* d_ws, size_t ws_size,
                              hipStream_t stream) {
  const float* q  = (const float*)d_in[0];
  const float* k  = (const float*)d_in[1];
  const float* Wq = (const float*)d_in[2];
  const float* Wk = (const float*)d_in[3];

  const size_t idx_elems = (size_t)NHEADS * TLEN * IDXD;   // 4M elements
  if (ws_size < 2 * idx_elems * sizeof(float)) return;     // need 32MB scratch

  float* qidx = (float*)d_ws;                  // [H][T][64] f32, 16MB
  float* kT   = (float*)d_ws + idx_elems;      // [H][64][T] f32, 16MB

  dim3 gproj(NPROJ / 64, TLEN / 64, 2);
  proj_both<<<gproj, 256, 0, stream>>>(q, k, Wq, Wk, qidx, kT);

  dim3 gsc(TLEN / 8, NHEADS);
  score_topk<<<gsc, 1024, 0, stream>>>(qidx, kT, (int*)d_out);
}